// Round 2
// baseline (203.659 us; speedup 1.0000x reference)
//
#include <hip/hip_runtime.h>
#include <hip/hip_bf16.h>

typedef __attribute__((ext_vector_type(4))) float f32x4;
typedef __attribute__((ext_vector_type(8))) short bf16x8;

#define T_LEN 2048
#define ENC   512
#define DEC   1024
#define ATT   128
#define NB    64
#define KP    544   // 512 keys + 31 conv taps + 1 zero pad
#define BM    64
#define BK    32
#define NXB   (T_LEN / BM)   // 32 tiles along T

__device__ __forceinline__ unsigned short f2bf(float x) {
  unsigned int u = __builtin_bit_cast(unsigned int, x);
  u += 0x7fff + ((u >> 16) & 1);   // RNE
  return (unsigned short)(u >> 16);
}

__device__ __forceinline__ float fast_tanh(float x) {
  float e = __expf(2.f * x);
  return 1.f - 2.f / (e + 1.f);    // robust at +-inf
}

// ---------------- prep 1: pq = query@W2  (b<64), CW = conv_w^T @ loc_dense (b==64)
__global__ __launch_bounds__(128) void prep1(
    const float* __restrict__ query, const float* __restrict__ W2,
    const float* __restrict__ convw, const float* __restrict__ ldense,
    float* __restrict__ pq, float* __restrict__ CW) {
  int a = threadIdx.x;
  int b = blockIdx.x;
  if (b < NB) {
    float acc = 0.f;
    for (int d = 0; d < DEC; ++d) acc += query[b * DEC + d] * W2[d * ATT + a];
    pq[b * ATT + a] = acc;
  } else {
    for (int k = 0; k < 31; ++k) {
      float acc = 0.f;
      #pragma unroll
      for (int f = 0; f < 32; ++f) acc += convw[f * 31 + k] * ldense[f * ATT + a];
      CW[k * ATT + a] = acc;
    }
  }
}

// ---------------- prep 2: BmatT[a][k] = bf16( k<512 ? W1[k][a] : k<543 ? CW[k-512][a] : 0 )
__global__ __launch_bounds__(256) void prep2(
    const float* __restrict__ W1, const float* __restrict__ CW,
    unsigned short* __restrict__ BmatT) {
  int a = blockIdx.x;
  for (int k = threadIdx.x; k < KP; k += 256) {
    float v = 0.f;
    if (k < 512) v = W1[k * ATT + a];
    else if (k < 543) v = CW[(k - 512) * ATT + a];
    BmatT[a * KP + k] = f2bf(v);
  }
}

// ---------------- main: barrier-free fused GEMM + tanh·V + mask + exp + partial ctx
__global__ __launch_bounds__(256, 4) void lsa_main(
    const float* __restrict__ keys, const float* __restrict__ prev,
    const int* __restrict__ mask, const unsigned short* __restrict__ BmatT,
    const float* __restrict__ pq, const float* __restrict__ Vv,
    float* __restrict__ wout, float* __restrict__ dpart, float* __restrict__ cpart) {
  __shared__ float s_red[2][BM];
  __shared__ float e_vals[BM];

  const int tid = threadIdx.x;
  const int b = blockIdx.y;
  const int trow0 = blockIdx.x * BM;
  const int bid = b * NXB + blockIdx.x;

  const int lane = tid & 63;
  const int w = tid >> 6;
  const int wr = w >> 1, wc = w & 1;         // wave tile: rows wr*32, cols wc*64
  const int rsel = lane & 15, grp = lane >> 4;

  f32x4 acc[2][4];
  #pragma unroll
  for (int m = 0; m < 2; ++m)
    #pragma unroll
    for (int n = 0; n < 4; ++n) acc[m][n] = (f32x4)0.f;

  // A fragment source: keys[row = trow0 + wr*32 + m*16 + rsel][kt*32 + grp*8 ..+8]
  const float* arow0 = keys + ((size_t)b * T_LEN + trow0 + wr * 32 + rsel) * ENC + grp * 8;
  const float* arow1 = arow0 + 16 * ENC;
  // B fragment source: BmatT[col = wc*64 + n*16 + rsel][kt*32 + grp*8 ..+8]
  const unsigned short* brow0 = BmatT + (size_t)(wc * 64 + rsel) * KP + grp * 8;

#define LOADA(dst, kt) do { \
    dst[0][0] = *reinterpret_cast<const f32x4*>(arow0 + (kt) * BK);     \
    dst[0][1] = *reinterpret_cast<const f32x4*>(arow0 + (kt) * BK + 4); \
    dst[1][0] = *reinterpret_cast<const f32x4*>(arow1 + (kt) * BK);     \
    dst[1][1] = *reinterpret_cast<const f32x4*>(arow1 + (kt) * BK + 4); } while (0)

#define LOADB(dst, kt) do { \
    dst[0] = *reinterpret_cast<const bf16x8*>(brow0 + (kt) * BK);            \
    dst[1] = *reinterpret_cast<const bf16x8*>(brow0 + 16 * KP + (kt) * BK);  \
    dst[2] = *reinterpret_cast<const bf16x8*>(brow0 + 32 * KP + (kt) * BK);  \
    dst[3] = *reinterpret_cast<const bf16x8*>(brow0 + 48 * KP + (kt) * BK); } while (0)

#define DOSTEP(ar, bn) do { \
    float t0[8], t1[8]; \
    *reinterpret_cast<f32x4*>(&t0[0]) = ar[0][0]; *reinterpret_cast<f32x4*>(&t0[4]) = ar[0][1]; \
    *reinterpret_cast<f32x4*>(&t1[0]) = ar[1][0]; *reinterpret_cast<f32x4*>(&t1[4]) = ar[1][1]; \
    bf16x8 af0, af1; \
    _Pragma("unroll") \
    for (int j = 0; j < 8; ++j) { af0[j] = (short)f2bf(t0[j]); af1[j] = (short)f2bf(t1[j]); } \
    _Pragma("unroll") \
    for (int n = 0; n < 4; ++n) { \
      acc[0][n] = __builtin_amdgcn_mfma_f32_16x16x32_bf16(af0, bn[n], acc[0][n], 0, 0, 0); \
      acc[1][n] = __builtin_amdgcn_mfma_f32_16x16x32_bf16(af1, bn[n], acc[1][n], 0, 0, 0); } } while (0)

  f32x4 arA[2][2], arB[2][2];
  bf16x8 bnA[4], bnB[4];
  LOADA(arA, 0); LOADB(bnA, 0);
  #pragma unroll
  for (int kt = 0; kt < 16; kt += 2) {
    LOADA(arB, kt + 1); LOADB(bnB, kt + 1);   // issue next before consuming cur
    DOSTEP(arA, bnA);
    if (kt + 2 < 16) { LOADA(arA, kt + 2); LOADB(bnA, kt + 2); }
    DOSTEP(arB, bnB);
  }

  // ---- step 16: conv-tap rows from prev_weights ----
  {
    bf16x8 bnP[4];
    LOADB(bnP, 16);
    bf16x8 af0, af1;
    const int trowm0 = trow0 + wr * 32 + rsel;
    #pragma unroll
    for (int j = 0; j < 8; ++j) {
      int kk = grp * 8 + j;
      float v0 = 0.f, v1 = 0.f;
      if (kk < 31) {
        int p0 = trowm0 + kk - 15;
        int p1 = p0 + 16;
        if (p0 >= 0 && p0 < T_LEN) v0 = prev[b * T_LEN + p0];
        if (p1 >= 0 && p1 < T_LEN) v1 = prev[b * T_LEN + p1];
      }
      af0[j] = (short)f2bf(v0);
      af1[j] = (short)f2bf(v1);
    }
    #pragma unroll
    for (int n = 0; n < 4; ++n) {
      acc[0][n] = __builtin_amdgcn_mfma_f32_16x16x32_bf16(af0, bnP[n], acc[0][n], 0, 0, 0);
      acc[1][n] = __builtin_amdgcn_mfma_f32_16x16x32_bf16(af1, bnP[n], acc[1][n], 0, 0, 0);
    }
  }

  // ---- epilogue: scores = sum_a V[a]*tanh(acc + pq) ----
  float psum[2][4];
  #pragma unroll
  for (int m = 0; m < 2; ++m)
    #pragma unroll
    for (int i = 0; i < 4; ++i) psum[m][i] = 0.f;
  #pragma unroll
  for (int n = 0; n < 4; ++n) {
    int c = wc * 64 + n * 16 + rsel;
    float pqv = pq[b * ATT + c];
    float vv = Vv[c];
    #pragma unroll
    for (int m = 0; m < 2; ++m)
      #pragma unroll
      for (int i = 0; i < 4; ++i)
        psum[m][i] += vv * fast_tanh(acc[m][n][i] + pqv);
  }
  #pragma unroll
  for (int m = 0; m < 2; ++m)
    #pragma unroll
    for (int i = 0; i < 4; ++i) {
      float v = psum[m][i];
      v += __shfl_xor(v, 1, 64);
      v += __shfl_xor(v, 2, 64);
      v += __shfl_xor(v, 4, 64);
      v += __shfl_xor(v, 8, 64);
      psum[m][i] = v;
    }
  if (rsel == 0) {
    #pragma unroll
    for (int m = 0; m < 2; ++m)
      #pragma unroll
      for (int i = 0; i < 4; ++i)
        s_red[wc][wr * 32 + m * 16 + grp * 4 + i] = psum[m][i];
  }
  __syncthreads();

  if (tid < BM) {
    int trow = trow0 + tid;
    float s = s_red[0][tid] + s_red[1][tid];
    float e = (mask[b * T_LEN + trow] == 0) ? 0.f : __expf(s);
    wout[b * T_LEN + trow] = e;       // unnormalized; finalize scales
    e_vals[tid] = e;
  }
  __syncthreads();

  if (tid < 64) {
    float v = e_vals[tid];
    #pragma unroll
    for (int off = 32; off; off >>= 1) v += __shfl_xor(v, off, 64);
    if (tid == 0) dpart[bid] = v;
  }

  // ---- partial context: sum_t e_t * keys[t,:], keys tile is L2/L3-hot ----
  float c0 = 0.f, c1 = 0.f;
  const float* krow = keys + ((size_t)b * T_LEN + trow0) * ENC;
  for (int r = 0; r < BM; ++r) {
    float e = e_vals[r];
    if (e != 0.f) {
      c0 += e * krow[(size_t)r * ENC + tid];
      c1 += e * krow[(size_t)r * ENC + tid + 256];
    }
  }
  cpart[(size_t)bid * ENC + tid] = c0;
  cpart[(size_t)bid * ENC + tid + 256] = c1;
}

// ---------------- finalize: normalize weights + reduce context partials
__global__ __launch_bounds__(256) void lsa_finalize(
    const float* __restrict__ dpart, const float* __restrict__ cpart,
    float* __restrict__ out) {
  int b = blockIdx.x, tid = threadIdx.x;
  float d = 0.f;
  #pragma unroll
  for (int i = 0; i < NXB; ++i) d += dpart[b * NXB + i];
  float inv = 1.f / d;
  for (int e = tid; e < ENC; e += 256) {
    float c = 0.f;
    #pragma unroll
    for (int i = 0; i < NXB; ++i) c += cpart[((size_t)(b * NXB + i)) * ENC + e];
    out[b * ENC + e] = c * inv;
  }
  float* wrow = out + NB * ENC + (size_t)b * T_LEN;
  for (int t = tid; t < T_LEN; t += 256) wrow[t] *= inv;
}

extern "C" void kernel_launch(void* const* d_in, const int* in_sizes, int n_in,
                              void* d_out, int out_size, void* d_ws, size_t ws_size,
                              hipStream_t stream) {
  const float* query  = (const float*)d_in[0];
  const float* keys   = (const float*)d_in[1];
  const float* prev   = (const float*)d_in[2];
  const int*   mask   = (const int*)d_in[3];
  const float* W1     = (const float*)d_in[4];
  const float* W2     = (const float*)d_in[5];
  const float* V      = (const float*)d_in[6];
  const float* convw  = (const float*)d_in[7];
  const float* ldense = (const float*)d_in[8];
  float* out = (float*)d_out;

  char* ws = (char*)d_ws;
  unsigned short* BmatT = (unsigned short*)ws;                    // 139264 B
  float* pq    = (float*)(ws + 139264);                           // 32768 B
  float* CW    = (float*)(ws + 139264 + 32768);                   // 15872 B
  float* dpart = (float*)(ws + 139264 + 32768 + 15872);           // 8192 B
  float* cpart = (float*)(ws + 139264 + 32768 + 15872 + 8192);    // 4 MB

  prep1<<<dim3(65), dim3(128), 0, stream>>>(query, W2, convw, ldense, pq, CW);
  prep2<<<dim3(128), dim3(256), 0, stream>>>(W1, CW, BmatT);
  dim3 grid(NXB, NB);
  lsa_main<<<grid, dim3(256), 0, stream>>>(keys, prev, mask, BmatT, pq, V,
                                           out + NB * ENC, dpart, cpart);
  lsa_finalize<<<dim3(NB), dim3(256), 0, stream>>>(dpart, cpart, out);
}

// Round 3
// 144.751 us; speedup vs baseline: 1.4070x; 1.4070x over previous
//
#include <hip/hip_runtime.h>

typedef __attribute__((ext_vector_type(4))) float f32x4;
typedef __attribute__((ext_vector_type(8))) short bf16x8;

#define T_LEN 2048
#define ENC   512
#define DEC   1024
#define ATT   128
#define NB    64
#define BM    128
#define BK    32
#define NXB   (T_LEN / BM)   // 16
#define NSTEP 17             // 16 keys steps + 1 conv-tap step

__device__ __forceinline__ unsigned short f2bf_rne(float x) {
  unsigned int u = __builtin_bit_cast(unsigned int, x);
  u += 0x7fff + ((u >> 16) & 1);
  return (unsigned short)(u >> 16);
}
// round-half-up: same 0.5-ulp max error as RNE, 2 VALU ops
__device__ __forceinline__ short f2bf_fast(float x) {
  unsigned int u = __builtin_bit_cast(unsigned int, x);
  return (short)((u + 0x8000u) >> 16);
}

__device__ __forceinline__ float fast_tanh(float x) {
  float e = __expf(2.f * x);
  return 1.f - 2.f / (e + 1.f);    // robust at +-inf
}

// ---------------- prep: pq = query@W2 (blocks 0..63); Bl frag-major B (blocks 64..191)
// Bl[kt][col][kk] bf16, flat = (kt*128 + col)*32 + kk, kt<17, col<128, kk<32
__global__ __launch_bounds__(128) void prep(
    const float* __restrict__ query, const float* __restrict__ W2,
    const float* __restrict__ W1, const float* __restrict__ convw,
    const float* __restrict__ ldense,
    float* __restrict__ pq, unsigned short* __restrict__ Bl) {
  int bidx = blockIdx.x;
  if (bidx < NB) {
    int a = threadIdx.x;
    float acc = 0.f;
    for (int d = 0; d < DEC; ++d) acc += query[bidx * DEC + d] * W2[d * ATT + a];
    pq[bidx * ATT + a] = acc;
  } else {
    int a = bidx - NB;   // output column 0..127
    for (int k = threadIdx.x; k < NSTEP * BK; k += 128) {
      float v = 0.f;
      if (k < 512) {
        v = W1[k * ATT + a];
      } else if (k < 543) {
        int kc = k - 512;
        #pragma unroll
        for (int f = 0; f < 32; ++f) v += convw[f * 31 + kc] * ldense[f * ATT + a];
      }
      int kt = k >> 5, kk = k & 31;
      Bl[(kt * 128 + a) * BK + kk] = f2bf_rne(v);
    }
  }
}

// ---------------- main: 2-phase pipelined fused GEMM + tanh.V + mask + exp + partial ctx
__global__ __launch_bounds__(256, 4) void lsa_main(
    const float* __restrict__ keys, const float* __restrict__ prev,
    const int* __restrict__ mask, const unsigned short* __restrict__ Bl,
    const float* __restrict__ pq, const float* __restrict__ Vv,
    float* __restrict__ wout, float* __restrict__ dpart, float* __restrict__ cpart) {
  __shared__ unsigned short Abf[2][BM * BK];   // 8 KB per buffer, swizzled bf16
  __shared__ float s_red[2][BM];
  __shared__ float e_vals[BM];

  const int tid = threadIdx.x;
  const int b = blockIdx.y;
  const int trow0 = blockIdx.x * BM;
  const int bid = b * NXB + blockIdx.x;

  const int lane = tid & 63;
  const int w = tid >> 6;
  const int wr = w >> 1, wc = w & 1;          // 2x2 waves, tile 64 rows x 64 cols
  const int rsel = lane & 15, grp = lane >> 4;

  // staging: thread covers row srow, 16 consecutive k (khalf)
  const int srow = tid >> 1;
  const int khalf = tid & 1;
  const int sq = (srow >> 1) & 3;              // write-side swizzle key
  const int widx0 = srow * BK + (((khalf * 2 + 0) ^ sq) * 8);
  const int widx1 = srow * BK + (((khalf * 2 + 1) ^ sq) * 8);

  const float* gA = keys + ((size_t)b * T_LEN + trow0 + srow) * ENC + khalf * 16;
  const unsigned short* gB = Bl + (size_t)(wc * 64 + rsel) * BK + grp * 8;

  // read-side fragment index: row = wr*64 + m*16 + rsel, slot = grp ^ ((rsel>>1)&3)
  const int rq = (rsel >> 1) & 3;
  const int ridx_base = (wr * 64 + rsel) * BK + ((grp ^ rq) * 8);

  f32x4 acc[4][4];
  #pragma unroll
  for (int m = 0; m < 4; ++m)
    #pragma unroll
    for (int n = 0; n < 4; ++n) acc[m][n] = (f32x4)0.f;

  // ---- prologue: stage step 0 ----
  {
    float a0[16];
    const f32x4* g = reinterpret_cast<const f32x4*>(gA);
    *reinterpret_cast<f32x4*>(&a0[0])  = g[0];
    *reinterpret_cast<f32x4*>(&a0[4])  = g[1];
    *reinterpret_cast<f32x4*>(&a0[8])  = g[2];
    *reinterpret_cast<f32x4*>(&a0[12]) = g[3];
    bf16x8 p0, p1;
    #pragma unroll
    for (int j = 0; j < 8; ++j) { p0[j] = f2bf_fast(a0[j]); p1[j] = f2bf_fast(a0[8 + j]); }
    *reinterpret_cast<bf16x8*>(&Abf[0][widx0]) = p0;
    *reinterpret_cast<bf16x8*>(&Abf[0][widx1]) = p1;
  }
  __syncthreads();

  #pragma unroll
  for (int t = 0; t < NSTEP; ++t) {
    // issue B(t) loads (L2-hot, 139 KB total)
    bf16x8 bfr[4];
    {
      const unsigned short* gBt = gB + (size_t)t * (128 * BK);
      #pragma unroll
      for (int n = 0; n < 4; ++n)
        bfr[n] = *reinterpret_cast<const bf16x8*>(gBt + n * 16 * BK);
    }
    // issue A(t+1) prefetch loads (HBM/L3)
    float anext[16];
    if (t < 15) {
      const f32x4* g = reinterpret_cast<const f32x4*>(gA + (t + 1) * BK);
      *reinterpret_cast<f32x4*>(&anext[0])  = g[0];
      *reinterpret_cast<f32x4*>(&anext[4])  = g[1];
      *reinterpret_cast<f32x4*>(&anext[8])  = g[2];
      *reinterpret_cast<f32x4*>(&anext[12]) = g[3];
    } else if (t == 15) {
      // conv-tap step: A[row][kk] = prev[trow0+row+kk-15], kk<31
      const int base = trow0 + srow + khalf * 16 - 15;
      #pragma unroll
      for (int j = 0; j < 16; ++j) {
        int kk = khalf * 16 + j;
        int pos = base + j;
        anext[j] = (kk < 31 && pos >= 0 && pos < T_LEN) ? prev[b * T_LEN + pos] : 0.f;
      }
    }
    // compute on buf[t&1]
    {
      const unsigned short* Ab = Abf[t & 1];
      #pragma unroll
      for (int m = 0; m < 4; ++m) {
        bf16x8 af = *reinterpret_cast<const bf16x8*>(&Ab[ridx_base + m * 16 * BK]);
        #pragma unroll
        for (int n = 0; n < 4; ++n)
          acc[m][n] = __builtin_amdgcn_mfma_f32_16x16x32_bf16(af, bfr[n], acc[m][n], 0, 0, 0);
      }
    }
    // convert + write staged tile, single barrier per step
    if (t < NSTEP - 1) {
      bf16x8 p0, p1;
      #pragma unroll
      for (int j = 0; j < 8; ++j) { p0[j] = f2bf_fast(anext[j]); p1[j] = f2bf_fast(anext[8 + j]); }
      unsigned short* Aw = Abf[(t + 1) & 1];
      *reinterpret_cast<bf16x8*>(&Aw[widx0]) = p0;
      *reinterpret_cast<bf16x8*>(&Aw[widx1]) = p1;
      __syncthreads();
    }
  }

  // ---- epilogue: scores = sum_a V[a]*tanh(acc + pq) ----
  float psum[4][4];
  #pragma unroll
  for (int m = 0; m < 4; ++m)
    #pragma unroll
    for (int i = 0; i < 4; ++i) psum[m][i] = 0.f;
  #pragma unroll
  for (int n = 0; n < 4; ++n) {
    int c = wc * 64 + n * 16 + rsel;
    float pqv = pq[b * ATT + c];
    float vv = Vv[c];
    #pragma unroll
    for (int m = 0; m < 4; ++m)
      #pragma unroll
      for (int i = 0; i < 4; ++i)
        psum[m][i] += vv * fast_tanh(acc[m][n][i] + pqv);
  }
  #pragma unroll
  for (int m = 0; m < 4; ++m)
    #pragma unroll
    for (int i = 0; i < 4; ++i) {
      float v = psum[m][i];
      v += __shfl_xor(v, 1, 64);
      v += __shfl_xor(v, 2, 64);
      v += __shfl_xor(v, 4, 64);
      v += __shfl_xor(v, 8, 64);
      psum[m][i] = v;
    }
  if (rsel == 0) {
    #pragma unroll
    for (int m = 0; m < 4; ++m)
      #pragma unroll
      for (int i = 0; i < 4; ++i)
        s_red[wc][wr * 64 + m * 16 + grp * 4 + i] = psum[m][i];
  }
  __syncthreads();

  if (tid < BM) {
    int trow = trow0 + tid;
    float s = s_red[0][tid] + s_red[1][tid];
    float e = (mask[b * T_LEN + trow] == 0) ? 0.f : __expf(s);
    wout[b * T_LEN + trow] = e;       // unnormalized; finalize scales
    e_vals[tid] = e;
  }
  __syncthreads();

  if (tid < 64) {
    float v = e_vals[tid] + e_vals[tid + 64];
    #pragma unroll
    for (int off = 32; off; off >>= 1) v += __shfl_xor(v, off, 64);
    if (tid == 0) dpart[bid] = v;
  }

  // ---- partial context: sum_t e_t * keys[t,:] (tile is L2-hot, ~half rows masked) ----
  float c0 = 0.f, c1 = 0.f;
  const float* krow = keys + ((size_t)b * T_LEN + trow0) * ENC;
  #pragma unroll 4
  for (int r = 0; r < BM; ++r) {
    float e = e_vals[r];
    if (e != 0.f) {
      c0 += e * krow[(size_t)r * ENC + tid];
      c1 += e * krow[(size_t)r * ENC + tid + 256];
    }
  }
  cpart[(size_t)bid * ENC + tid] = c0;
  cpart[(size_t)bid * ENC + tid + 256] = c1;
}

// ---------------- finalize: normalize weights + reduce context partials
__global__ __launch_bounds__(256) void lsa_finalize(
    const float* __restrict__ dpart, const float* __restrict__ cpart,
    float* __restrict__ out) {
  int b = blockIdx.x, tid = threadIdx.x;
  float d = 0.f;
  #pragma unroll
  for (int i = 0; i < NXB; ++i) d += dpart[b * NXB + i];
  float inv = 1.f / d;
  for (int e = tid; e < ENC; e += 256) {
    float c = 0.f;
    #pragma unroll
    for (int i = 0; i < NXB; ++i) c += cpart[((size_t)(b * NXB + i)) * ENC + e];
    out[b * ENC + e] = c * inv;
  }
  float* wrow = out + NB * ENC + (size_t)b * T_LEN;
  for (int t = tid; t < T_LEN; t += 256) wrow[t] *= inv;
}

extern "C" void kernel_launch(void* const* d_in, const int* in_sizes, int n_in,
                              void* d_out, int out_size, void* d_ws, size_t ws_size,
                              hipStream_t stream) {
  const float* query  = (const float*)d_in[0];
  const float* keys   = (const float*)d_in[1];
  const float* prev   = (const float*)d_in[2];
  const int*   mask   = (const int*)d_in[3];
  const float* W1     = (const float*)d_in[4];
  const float* W2     = (const float*)d_in[5];
  const float* V      = (const float*)d_in[6];
  const float* convw  = (const float*)d_in[7];
  const float* ldense = (const float*)d_in[8];
  float* out = (float*)d_out;

  char* ws = (char*)d_ws;
  unsigned short* Bl = (unsigned short*)ws;                       // 139264 B
  float* pq    = (float*)(ws + 139264);                           // 32768 B
  float* dpart = (float*)(ws + 139264 + 32768);                   // 4096 B
  float* cpart = (float*)(ws + 139264 + 32768 + 4096);            // 2 MB

  prep<<<dim3(192), dim3(128), 0, stream>>>(query, W2, W1, convw, ldense, pq, Bl);
  dim3 grid(NXB, NB);
  lsa_main<<<grid, dim3(256), 0, stream>>>(keys, prev, mask, Bl, pq, V,
                                           out + NB * ENC, dpart, cpart);
  lsa_finalize<<<dim3(NB), dim3(256), 0, stream>>>(dpart, cpart, out);
}

// Round 4
// 135.490 us; speedup vs baseline: 1.5031x; 1.0684x over previous
//
#include <hip/hip_runtime.h>

typedef __attribute__((ext_vector_type(4))) float f32x4;
typedef __attribute__((ext_vector_type(8))) short bf16x8;

#define T_LEN 2048
#define ENC   512
#define DEC   1024
#define ATT   128
#define NB    64
#define BM    128
#define BK    32
#define NXB   (T_LEN / BM)   // 16
#define NSTEP 17             // 16 keys steps + 1 conv-tap step

typedef unsigned int u32;
typedef __attribute__((address_space(1))) const u32 gu32;
typedef __attribute__((address_space(3))) u32 lu32;

__device__ __forceinline__ void async_copy16(const float* g, float* l) {
  __builtin_amdgcn_global_load_lds((gu32*)g, (lu32*)l, 16, 0, 0);
}

__device__ __forceinline__ unsigned short f2bf_rne(float x) {
  unsigned int u = __builtin_bit_cast(unsigned int, x);
  u += 0x7fff + ((u >> 16) & 1);
  return (unsigned short)(u >> 16);
}
// round-half-up: same 0.5-ulp max error, 2 VALU ops
__device__ __forceinline__ short f2bf_fast(float x) {
  unsigned int u = __builtin_bit_cast(unsigned int, x);
  return (short)((u + 0x8000u) >> 16);
}

__device__ __forceinline__ float fast_tanh(float x) {
  float e = __expf(2.f * x);
  return 1.f - 2.f / (e + 1.f);    // robust at +-inf
}

// ---------------- prep: pq = query@W2 (blocks 0..63); Bl frag-major B (blocks 64..191)
// Bl[kt][col][kk] bf16, flat = (kt*128 + col)*32 + kk
__global__ __launch_bounds__(128) void prep(
    const float* __restrict__ query, const float* __restrict__ W2,
    const float* __restrict__ W1, const float* __restrict__ convw,
    const float* __restrict__ ldense,
    float* __restrict__ pq, unsigned short* __restrict__ Bl) {
  int bidx = blockIdx.x;
  if (bidx < NB) {
    int a = threadIdx.x;
    float acc = 0.f;
    for (int d = 0; d < DEC; ++d) acc += query[bidx * DEC + d] * W2[d * ATT + a];
    pq[bidx * ATT + a] = acc;
  } else {
    int a = bidx - NB;   // output column 0..127
    for (int k = threadIdx.x; k < NSTEP * BK; k += 128) {
      float v = 0.f;
      if (k < 512) {
        v = W1[k * ATT + a];
      } else if (k < 543) {
        int kc = k - 512;
        #pragma unroll
        for (int f = 0; f < 32; ++f) v += convw[f * 31 + kc] * ldense[f * ATT + a];
      }
      int kt = k >> 5, kk = k & 31;
      Bl[(kt * 128 + a) * BK + kk] = f2bf_rne(v);
    }
  }
}

// ---------------- main: gload_lds double-buffered GEMM + tanh.V + mask + exp + partial ctx
__global__ __launch_bounds__(256, 4) void lsa_main(
    const float* __restrict__ keys, const float* __restrict__ prev,
    const int* __restrict__ mask, const unsigned short* __restrict__ Bl,
    const float* __restrict__ pq, const float* __restrict__ Vv,
    float* __restrict__ wout, float* __restrict__ dpart, float* __restrict__ cpart) {
  __shared__ float Abf[2][BM * BK];   // fp32 tiles, 16 KB each, chunk-swizzled
  __shared__ float s_red[2][BM];
  __shared__ float e_vals[BM];

  const int tid = threadIdx.x;
  const int b = blockIdx.y;
  const int trow0 = blockIdx.x * BM;
  const int bid = b * NXB + blockIdx.x;

  const int lane = tid & 63;
  const int w = tid >> 6;
  const int wr = w >> 1, wc = w & 1;          // 2x2 waves, wave tile 64x64
  const int rsel = lane & 15, grp = lane >> 4;

  // ---- gload_lds staging geometry ----
  // call i of wave w covers global rows w*32+i*8 .. +8, LDS linear [r][c'] (c' = 16B chunk)
  // swizzle: LDS phys chunk c' holds logical chunk c = c' ^ (r&7); note (r&7) == lr
  const int lr = lane >> 3, cp = lane & 7;
  const int gr = w * 32 + lr;
  const int gc = cp ^ lr;                     // logical chunk for this lane
  const float* gA = keys + ((size_t)b * T_LEN + trow0 + gr) * ENC + gc * 4;

  // B fragments direct from L2: col = wc*64 + n*16 + rsel, k-slot grp
  const unsigned short* gB = Bl + (size_t)(wc * 64 + rsel) * BK + grp * 8;

  // A fragment read: row r = wr*64 + m*16 + rsel; logical chunks 2g,2g+1; (r&7)==(rsel&7)
  const int rx = rsel & 7;
  const int ca0 = (2 * grp) ^ rx, ca1 = (2 * grp + 1) ^ rx;
  const int arow_base = (wr * 64 + rsel) * BK;    // floats

  f32x4 acc[4][4];
  #pragma unroll
  for (int m = 0; m < 4; ++m)
    #pragma unroll
    for (int n = 0; n < 4; ++n) acc[m][n] = (f32x4)0.f;

  // ---- prologue: stage step 0 into Abf[0] ----
  #pragma unroll
  for (int i = 0; i < 4; ++i)
    async_copy16(gA + (size_t)i * 8 * ENC, &Abf[0][(w * 4 + i) * 256]);
  __syncthreads();

  for (int t = 0; t < 16; ++t) {
    // ---- issue next-tile staging (async, not drained until barrier) ----
    if (t < 15) {
      const float* gt = gA + (t + 1) * BK;
      float* dst = &Abf[(t + 1) & 1][0];
      #pragma unroll
      for (int i = 0; i < 4; ++i)
        async_copy16(gt + (size_t)i * 8 * ENC, &dst[(w * 4 + i) * 256]);
    } else {
      // stage conv-tap tile into Abf[0]: A16[r][kk] = prev[trow0+r+kk-15], kk<31
      const int r = tid >> 1, kh = tid & 1;
      const int rx2 = r & 7;
      float* dst = &Abf[0][r * BK];
      #pragma unroll
      for (int jc = 0; jc < 4; ++jc) {
        int c = kh * 4 + jc;
        f32x4 v;
        #pragma unroll
        for (int q = 0; q < 4; ++q) {
          int kk = c * 4 + q;
          int pos = trow0 + r + kk - 15;
          v[q] = (kk < 31 && pos >= 0 && pos < T_LEN) ? prev[b * T_LEN + pos] : 0.f;
        }
        *reinterpret_cast<f32x4*>(&dst[(c ^ rx2) * 4]) = v;
      }
    }
    // ---- B fragments for step t (L2-hot) ----
    bf16x8 bfr[4];
    {
      const unsigned short* gBt = gB + (size_t)t * (128 * BK);
      #pragma unroll
      for (int n = 0; n < 4; ++n)
        bfr[n] = *reinterpret_cast<const bf16x8*>(gBt + n * 16 * BK);
    }
    // ---- compute step t from Abf[t&1] ----
    {
      const float* Ab = &Abf[t & 1][0];
      #pragma unroll
      for (int m = 0; m < 4; ++m) {
        f32x4 x0 = *reinterpret_cast<const f32x4*>(&Ab[arow_base + m * 16 * BK + ca0 * 4]);
        f32x4 x1 = *reinterpret_cast<const f32x4*>(&Ab[arow_base + m * 16 * BK + ca1 * 4]);
        bf16x8 af;
        #pragma unroll
        for (int j = 0; j < 4; ++j) { af[j] = f2bf_fast(x0[j]); af[4 + j] = f2bf_fast(x1[j]); }
        #pragma unroll
        for (int n = 0; n < 4; ++n)
          acc[m][n] = __builtin_amdgcn_mfma_f32_16x16x32_bf16(af, bfr[n], acc[m][n], 0, 0, 0);
      }
    }
    __syncthreads();
  }
  // ---- final step t=16 (conv taps) from Abf[0] ----
  {
    bf16x8 bfr[4];
    const unsigned short* gBt = gB + (size_t)16 * (128 * BK);
    #pragma unroll
    for (int n = 0; n < 4; ++n)
      bfr[n] = *reinterpret_cast<const bf16x8*>(gBt + n * 16 * BK);
    const float* Ab = &Abf[0][0];
    #pragma unroll
    for (int m = 0; m < 4; ++m) {
      f32x4 x0 = *reinterpret_cast<const f32x4*>(&Ab[arow_base + m * 16 * BK + ca0 * 4]);
      f32x4 x1 = *reinterpret_cast<const f32x4*>(&Ab[arow_base + m * 16 * BK + ca1 * 4]);
      bf16x8 af;
      #pragma unroll
      for (int j = 0; j < 4; ++j) { af[j] = f2bf_fast(x0[j]); af[4 + j] = f2bf_fast(x1[j]); }
      #pragma unroll
      for (int n = 0; n < 4; ++n)
        acc[m][n] = __builtin_amdgcn_mfma_f32_16x16x32_bf16(af, bfr[n], acc[m][n], 0, 0, 0);
    }
  }

  // ---- epilogue: scores = sum_a V[a]*tanh(acc + pq) ----
  float psum[4][4];
  #pragma unroll
  for (int m = 0; m < 4; ++m)
    #pragma unroll
    for (int i = 0; i < 4; ++i) psum[m][i] = 0.f;
  #pragma unroll
  for (int n = 0; n < 4; ++n) {
    int c = wc * 64 + n * 16 + rsel;
    float pqv = pq[b * ATT + c];
    float vv = Vv[c];
    #pragma unroll
    for (int m = 0; m < 4; ++m)
      #pragma unroll
      for (int i = 0; i < 4; ++i)
        psum[m][i] += vv * fast_tanh(acc[m][n][i] + pqv);
  }
  #pragma unroll
  for (int m = 0; m < 4; ++m)
    #pragma unroll
    for (int i = 0; i < 4; ++i) {
      float v = psum[m][i];
      v += __shfl_xor(v, 1, 64);
      v += __shfl_xor(v, 2, 64);
      v += __shfl_xor(v, 4, 64);
      v += __shfl_xor(v, 8, 64);
      psum[m][i] = v;
    }
  if (rsel == 0) {
    #pragma unroll
    for (int m = 0; m < 4; ++m)
      #pragma unroll
      for (int i = 0; i < 4; ++i)
        s_red[wc][wr * 64 + m * 16 + grp * 4 + i] = psum[m][i];
  }
  __syncthreads();

  if (tid < BM) {
    int trow = trow0 + tid;
    float s = s_red[0][tid] + s_red[1][tid];
    float e = (mask[b * T_LEN + trow] == 0) ? 0.f : __expf(s);
    wout[b * T_LEN + trow] = e;       // unnormalized; finalize scales
    e_vals[tid] = e;
  }
  __syncthreads();

  if (tid < 64) {
    float v = e_vals[tid] + e_vals[tid + 64];
    #pragma unroll
    for (int off = 32; off; off >>= 1) v += __shfl_xor(v, off, 64);
    if (tid == 0) dpart[bid] = v;
  }

  // ---- partial context: sum_t e_t * keys[t,:] (tile L2/L3-hot) ----
  float c0 = 0.f, c1 = 0.f;
  const float* krow = keys + ((size_t)b * T_LEN + trow0) * ENC;
  #pragma unroll 4
  for (int r = 0; r < BM; ++r) {
    float e = e_vals[r];
    if (e != 0.f) {
      c0 += e * krow[(size_t)r * ENC + tid];
      c1 += e * krow[(size_t)r * ENC + tid + 256];
    }
  }
  cpart[(size_t)bid * ENC + tid] = c0;
  cpart[(size_t)bid * ENC + tid + 256] = c1;
}

// ---------------- finalize: normalize weights + reduce context partials
__global__ __launch_bounds__(256) void lsa_finalize(
    const float* __restrict__ dpart, const float* __restrict__ cpart,
    float* __restrict__ out) {
  int b = blockIdx.x, tid = threadIdx.x;
  float d = 0.f;
  #pragma unroll
  for (int i = 0; i < NXB; ++i) d += dpart[b * NXB + i];
  float inv = 1.f / d;
  for (int e = tid; e < ENC; e += 256) {
    float c = 0.f;
    #pragma unroll
    for (int i = 0; i < NXB; ++i) c += cpart[((size_t)(b * NXB + i)) * ENC + e];
    out[b * ENC + e] = c * inv;
  }
  float* wrow = out + NB * ENC + (size_t)b * T_LEN;
  for (int t = tid; t < T_LEN; t += 256) wrow[t] *= inv;
}

extern "C" void kernel_launch(void* const* d_in, const int* in_sizes, int n_in,
                              void* d_out, int out_size, void* d_ws, size_t ws_size,
                              hipStream_t stream) {
  const float* query  = (const float*)d_in[0];
  const float* keys   = (const float*)d_in[1];
  const float* prev   = (const float*)d_in[2];
  const int*   mask   = (const int*)d_in[3];
  const float* W1     = (const float*)d_in[4];
  const float* W2     = (const float*)d_in[5];
  const float* V      = (const float*)d_in[6];
  const float* convw  = (const float*)d_in[7];
  const float* ldense = (const float*)d_in[8];
  float* out = (float*)d_out;

  char* ws = (char*)d_ws;
  unsigned short* Bl = (unsigned short*)ws;                       // 139264 B
  float* pq    = (float*)(ws + 139264);                           // 32768 B
  float* dpart = (float*)(ws + 139264 + 32768);                   // 4096 B
  float* cpart = (float*)(ws + 139264 + 32768 + 4096);            // 2 MB

  prep<<<dim3(192), dim3(128), 0, stream>>>(query, W2, W1, convw, ldense, pq, Bl);
  dim3 grid(NXB, NB);
  lsa_main<<<grid, dim3(256), 0, stream>>>(keys, prev, mask, Bl, pq, V,
                                           out + NB * ENC, dpart, cpart);
  lsa_finalize<<<dim3(NB), dim3(256), 0, stream>>>(dpart, cpart, out);
}

// Round 5
// 134.890 us; speedup vs baseline: 1.5098x; 1.0044x over previous
//
#include <hip/hip_runtime.h>

typedef __attribute__((ext_vector_type(4))) float f32x4;
typedef __attribute__((ext_vector_type(2))) float f32x2;
typedef __attribute__((ext_vector_type(8))) short bf16x8;

#define T_LEN 2048
#define ENC   512
#define DEC   1024
#define ATT   128
#define NB    64
#define BM    128
#define BK    32
#define NXB   (T_LEN / BM)   // 16

typedef unsigned int u32;
typedef __attribute__((address_space(1))) const u32 gu32;
typedef __attribute__((address_space(3))) u32 lu32;

__device__ __forceinline__ void async_copy16(const float* g, float* l) {
  __builtin_amdgcn_global_load_lds((gu32*)g, (lu32*)l, 16, 0, 0);
}

__device__ __forceinline__ unsigned short f2bf_rne(float x) {
  unsigned int u = __builtin_bit_cast(unsigned int, x);
  u += 0x7fff + ((u >> 16) & 1);
  return (unsigned short)(u >> 16);
}
// round-half-up: same 0.5-ulp max error, 2 VALU ops
__device__ __forceinline__ short f2bf_fast(float x) {
  unsigned int u = __builtin_bit_cast(unsigned int, x);
  return (short)((u + 0x8000u) >> 16);
}

__device__ __forceinline__ float fast_tanh(float x) {
  float e = __expf(2.f * x);
  return 1.f - 2.f / (e + 1.f);    // robust at +-inf
}

// ---------------- prep: pq = query@W2 (blocks 0..63); Bl frag-major B (blocks 64..191)
// Bl[kt][col][kk] bf16, flat = (kt*128 + col)*32 + kk
__global__ __launch_bounds__(128) void prep(
    const float* __restrict__ query, const float* __restrict__ W2,
    const float* __restrict__ W1, const float* __restrict__ convw,
    const float* __restrict__ ldense,
    float* __restrict__ pq, unsigned short* __restrict__ Bl) {
  int bidx = blockIdx.x;
  if (bidx < NB) {
    int a = threadIdx.x;
    const float* q = query + bidx * DEC;
    float a0 = 0.f, a1 = 0.f, a2 = 0.f, a3 = 0.f;
    for (int d = 0; d < DEC; d += 4) {
      a0 += q[d]     * W2[(d)     * ATT + a];
      a1 += q[d + 1] * W2[(d + 1) * ATT + a];
      a2 += q[d + 2] * W2[(d + 2) * ATT + a];
      a3 += q[d + 3] * W2[(d + 3) * ATT + a];
    }
    pq[bidx * ATT + a] = (a0 + a1) + (a2 + a3);
  } else {
    int a = bidx - NB;   // output column 0..127
    for (int k = threadIdx.x; k < 17 * BK; k += 128) {
      float v = 0.f;
      if (k < 512) {
        v = W1[k * ATT + a];
      } else if (k < 543) {
        int kc = k - 512;
        #pragma unroll
        for (int f = 0; f < 32; ++f) v += convw[f * 31 + kc] * ldense[f * ATT + a];
      }
      int kt = k >> 5, kk = k & 31;
      Bl[(kt * 128 + a) * BK + kk] = f2bf_rne(v);
    }
  }
}

// ---------------- main ----------------
__global__ __launch_bounds__(256, 4) void lsa_main(
    const float* __restrict__ keys, const float* __restrict__ prev,
    const int* __restrict__ mask, const unsigned short* __restrict__ Bl,
    const float* __restrict__ pq, const float* __restrict__ Vv,
    float* __restrict__ wout, float* __restrict__ dpart, float* __restrict__ cpart) {
  __shared__ float Abf[2][BM * BK];   // fp32 tiles, 16 KB each, chunk-swizzled
  __shared__ float s_red[2][BM];
  __shared__ float e_vals[BM];

  const int tid = threadIdx.x;
  const int b = blockIdx.y;
  const int trow0 = blockIdx.x * BM;
  const int bid = b * NXB + blockIdx.x;

  const int lane = tid & 63;
  const int w = tid >> 6;
  const int wr = w >> 1, wc = w & 1;          // 2x2 waves, wave tile 64x64
  const int rsel = lane & 15, grp = lane >> 4;

  // gload_lds staging geometry: lane covers row gr, 16B chunk cp; phys c' holds logical c'^(r&7)
  const int lr = lane >> 3, cp = lane & 7;
  const int gr = w * 32 + lr;
  const int gc = cp ^ lr;
  const float* gA = keys + ((size_t)b * T_LEN + trow0 + gr) * ENC + gc * 4;

  // B fragments direct from L2: col = wc*64 + n*16 + rsel, k-slot grp
  const unsigned short* gB = Bl + (size_t)(wc * 64 + rsel) * BK + grp * 8;

  // A fragment read: row r = wr*64 + m*16 + rsel; logical chunks 2g,2g+1; (r&7)==(rsel&7)
  const int rx = rsel & 7;
  const int ca0 = (2 * grp) ^ rx, ca1 = (2 * grp + 1) ^ rx;
  const int arow_base = (wr * 64 + rsel) * BK;

  f32x4 acc[4][4];
  #pragma unroll
  for (int m = 0; m < 4; ++m)
    #pragma unroll
    for (int n = 0; n < 4; ++n) acc[m][n] = (f32x4)0.f;

#define STAGE(t_, buf_) do { \
    const float* gt_ = gA + (t_) * BK; \
    float* dst_ = &Abf[buf_][0]; \
    _Pragma("unroll") \
    for (int i_ = 0; i_ < 4; ++i_) \
      async_copy16(gt_ + (size_t)i_ * 8 * ENC, &dst_[(w * 4 + i_) * 256]); } while (0)

#define STAGE_CONV() do { \
    const int r_ = tid >> 1, kh_ = tid & 1; \
    const int rx2_ = r_ & 7; \
    float* dst_ = &Abf[0][r_ * BK]; \
    _Pragma("unroll") \
    for (int jc_ = 0; jc_ < 4; ++jc_) { \
      int c_ = kh_ * 4 + jc_; \
      f32x4 v_; \
      _Pragma("unroll") \
      for (int q_ = 0; q_ < 4; ++q_) { \
        int kk_ = c_ * 4 + q_; \
        int pos_ = trow0 + r_ + kk_ - 15; \
        v_[q_] = (kk_ < 31 && pos_ >= 0 && pos_ < T_LEN) ? prev[b * T_LEN + pos_] : 0.f; \
      } \
      *reinterpret_cast<f32x4*>(&dst_[(c_ ^ rx2_) * 4]) = v_; \
    } } while (0)

#define LOADB(dst_, t_) do { \
    const unsigned short* gBt_ = gB + (size_t)(t_) * (128 * BK); \
    dst_[0] = *reinterpret_cast<const bf16x8*>(gBt_); \
    dst_[1] = *reinterpret_cast<const bf16x8*>(gBt_ + 16 * BK); \
    dst_[2] = *reinterpret_cast<const bf16x8*>(gBt_ + 32 * BK); \
    dst_[3] = *reinterpret_cast<const bf16x8*>(gBt_ + 48 * BK); } while (0)

#define COMPUTE(buf_, br_) do { \
    const float* Ab_ = &Abf[buf_][0]; \
    _Pragma("unroll") \
    for (int m_ = 0; m_ < 4; ++m_) { \
      f32x4 x0_ = *reinterpret_cast<const f32x4*>(&Ab_[arow_base + m_ * 16 * BK + ca0 * 4]); \
      f32x4 x1_ = *reinterpret_cast<const f32x4*>(&Ab_[arow_base + m_ * 16 * BK + ca1 * 4]); \
      bf16x8 af_; \
      _Pragma("unroll") \
      for (int j_ = 0; j_ < 4; ++j_) { af_[j_] = f2bf_fast(x0_[j_]); af_[4 + j_] = f2bf_fast(x1_[j_]); } \
      _Pragma("unroll") \
      for (int n_ = 0; n_ < 4; ++n_) \
        acc[m_][n_] = __builtin_amdgcn_mfma_f32_16x16x32_bf16(af_, br_[n_], acc[m_][n_], 0, 0, 0); \
    } } while (0)

  bf16x8 bA[4], bB[4];
  // prologue: stage tile 0, load B0
  STAGE(0, 0);
  LOADB(bA, 0);
  __syncthreads();

  #pragma unroll
  for (int tt = 0; tt < 16; tt += 2) {
    // even step t=tt (buf0, bA); prefetch B(tt+1), stage A(tt+1)->buf1
    LOADB(bB, tt + 1);
    STAGE(tt + 1, 1);
    COMPUTE(0, bA);
    __syncthreads();
    // odd step t=tt+1 (buf1, bB); prefetch B(tt+2), stage A(tt+2)->buf0 (conv tile when tt==14)
    LOADB(bA, tt + 2);
    if (tt < 14) STAGE(tt + 2, 0); else STAGE_CONV();
    COMPUTE(1, bB);
    __syncthreads();
  }
  // t=16: conv-tap step (buf0, bA=B16)
  COMPUTE(0, bA);

  // ---- epilogue: scores = sum_a V[a]*tanh(acc + pq) ----
  float psum[4][4];
  #pragma unroll
  for (int m = 0; m < 4; ++m)
    #pragma unroll
    for (int i = 0; i < 4; ++i) psum[m][i] = 0.f;
  #pragma unroll
  for (int n = 0; n < 4; ++n) {
    int c = wc * 64 + n * 16 + rsel;
    float pqv = pq[b * ATT + c];
    float vv = Vv[c];
    #pragma unroll
    for (int m = 0; m < 4; ++m)
      #pragma unroll
      for (int i = 0; i < 4; ++i)
        psum[m][i] += vv * fast_tanh(acc[m][n][i] + pqv);
  }
  #pragma unroll
  for (int m = 0; m < 4; ++m)
    #pragma unroll
    for (int i = 0; i < 4; ++i) {
      float v = psum[m][i];
      v += __shfl_xor(v, 1, 64);
      v += __shfl_xor(v, 2, 64);
      v += __shfl_xor(v, 4, 64);
      v += __shfl_xor(v, 8, 64);
      psum[m][i] = v;
    }
  if (rsel == 0) {
    #pragma unroll
    for (int m = 0; m < 4; ++m)
      #pragma unroll
      for (int i = 0; i < 4; ++i)
        s_red[wc][wr * 64 + m * 16 + grp * 4 + i] = psum[m][i];
  }
  __syncthreads();

  if (tid < BM) {
    int trow = trow0 + tid;
    float s = s_red[0][tid] + s_red[1][tid];
    float e = (mask[b * T_LEN + trow] == 0) ? 0.f : __expf(s);
    wout[b * T_LEN + trow] = e;       // unnormalized; finalize scales
    e_vals[tid] = e;
  }
  __syncthreads();

  if (tid < 64) {
    float v = e_vals[tid] + e_vals[tid + 64];
    #pragma unroll
    for (int off = 32; off; off >>= 1) v += __shfl_xor(v, off, 64);
    if (tid == 0) dpart[bid] = v;
  }

  // ---- partial context: branch-free, float2, pipelined (tile is L2-hot) ----
  {
    const float* kcol = keys + ((size_t)b * T_LEN + trow0) * ENC + 2 * tid;
    f32x2 cacc; cacc.x = 0.f; cacc.y = 0.f;
    #pragma unroll 8
    for (int r = 0; r < BM; ++r) {
      float e = e_vals[r];
      f32x2 kv = *reinterpret_cast<const f32x2*>(kcol + (size_t)r * ENC);
      cacc.x += e * kv.x;
      cacc.y += e * kv.y;
    }
    *reinterpret_cast<f32x2*>(cpart + (size_t)bid * ENC + 2 * tid) = cacc;
  }
}

// ---------------- finalize: normalize weights + reduce context partials
__global__ __launch_bounds__(256) void lsa_finalize(
    const float* __restrict__ dpart, const float* __restrict__ cpart,
    float* __restrict__ out) {
  int b = blockIdx.x, tid = threadIdx.x;
  float d = 0.f;
  #pragma unroll
  for (int i = 0; i < NXB; ++i) d += dpart[b * NXB + i];
  float inv = 1.f / d;
  for (int e = tid; e < ENC; e += 256) {
    float c = 0.f;
    #pragma unroll
    for (int i = 0; i < NXB; ++i) c += cpart[((size_t)(b * NXB + i)) * ENC + e];
    out[b * ENC + e] = c * inv;
  }
  float* wrow = out + NB * ENC + (size_t)b * T_LEN;
  for (int t = tid; t < T_LEN; t += 256) wrow[t] *= inv;
}

extern "C" void kernel_launch(void* const* d_in, const int* in_sizes, int n_in,
                              void* d_out, int out_size, void* d_ws, size_t ws_size,
                              hipStream_t stream) {
  const float* query  = (const float*)d_in[0];
  const float* keys   = (const float*)d_in[1];
  const float* prev   = (const float*)d_in[2];
  const int*   mask   = (const int*)d_in[3];
  const float* W1     = (const float*)d_in[4];
  const float* W2     = (const float*)d_in[5];
  const float* V      = (const float*)d_in[6];
  const float* convw  = (const float*)d_in[7];
  const float* ldense = (const float*)d_in[8];
  float* out = (float*)d_out;

  char* ws = (char*)d_ws;
  unsigned short* Bl = (unsigned short*)ws;                       // 139264 B
  float* pq    = (float*)(ws + 139264);                           // 32768 B
  float* dpart = (float*)(ws + 139264 + 32768);                   // 4096 B
  float* cpart = (float*)(ws + 139264 + 32768 + 4096);            // 2 MB

  prep<<<dim3(192), dim3(128), 0, stream>>>(query, W2, W1, convw, ldense, pq, Bl);
  dim3 grid(NXB, NB);
  lsa_main<<<grid, dim3(256), 0, stream>>>(keys, prev, mask, Bl, pq, V,
                                           out + NB * ENC, dpart, cpart);
  lsa_finalize<<<dim3(NB), dim3(256), 0, stream>>>(dpart, cpart, out);
}

// Round 7
// 130.291 us; speedup vs baseline: 1.5631x; 1.0353x over previous
//
#include <hip/hip_runtime.h>

typedef __attribute__((ext_vector_type(4))) float f32x4;
typedef __attribute__((ext_vector_type(2))) float f32x2;
typedef __attribute__((ext_vector_type(8))) short bf16x8;

#define T_LEN 2048
#define ENC   512
#define DEC   1024
#define ATT   128
#define NB    64
#define BM    128
#define BK    32
#define NXB   (T_LEN / BM)   // 16

typedef unsigned int u32;
typedef __attribute__((address_space(1))) const u32 gu32;
typedef __attribute__((address_space(3))) u32 lu32;

__device__ __forceinline__ void async_copy16(const void* g, void* l) {
  __builtin_amdgcn_global_load_lds((gu32*)g, (lu32*)l, 16, 0, 0);
}

__device__ __forceinline__ unsigned short f2bf_rne(float x) {
  unsigned int u = __builtin_bit_cast(unsigned int, x);
  u += 0x7fff + ((u >> 16) & 1);
  return (unsigned short)(u >> 16);
}
// round-half-up: same 0.5-ulp max error, 2 VALU ops
__device__ __forceinline__ short f2bf_fast(float x) {
  unsigned int u = __builtin_bit_cast(unsigned int, x);
  return (short)((u + 0x8000u) >> 16);
}

__device__ __forceinline__ float fast_tanh(float x) {
  float e = __expf(2.f * x);
  return 1.f - 2.f / (e + 1.f);    // robust at +-inf
}

// ---------------- prep: pq = query@W2 (blocks 0..63); Bl chunk-major (blocks 64..191)
// Bl layout: step t (0..16), chunk c=kk>>3 (0..3), col a (0..127), 8 shorts (kk&7)
// flat short index: ((t*4 + c)*128 + a)*8 + (kk&7)   -> staging is identity-mapped
__global__ __launch_bounds__(128) void prep(
    const float* __restrict__ query, const float* __restrict__ W2,
    const float* __restrict__ W1, const float* __restrict__ convw,
    const float* __restrict__ ldense,
    float* __restrict__ pq, unsigned short* __restrict__ Bl) {
  int bidx = blockIdx.x;
  if (bidx < NB) {
    int a = threadIdx.x;
    const float* q = query + bidx * DEC;
    float a0 = 0.f, a1 = 0.f, a2 = 0.f, a3 = 0.f;
    for (int d = 0; d < DEC; d += 4) {
      a0 += q[d]     * W2[(d)     * ATT + a];
      a1 += q[d + 1] * W2[(d + 1) * ATT + a];
      a2 += q[d + 2] * W2[(d + 2) * ATT + a];
      a3 += q[d + 3] * W2[(d + 3) * ATT + a];
    }
    pq[bidx * ATT + a] = (a0 + a1) + (a2 + a3);
  } else {
    int a = bidx - NB;   // output column 0..127
    for (int k = threadIdx.x; k < 17 * BK; k += 128) {
      float v = 0.f;
      if (k < 512) {
        v = W1[k * ATT + a];
      } else if (k < 543) {
        int kc = k - 512;
        #pragma unroll
        for (int f = 0; f < 32; ++f) v += convw[f * 31 + kc] * ldense[f * ATT + a];
      }
      int kt = k >> 5, kk = k & 31;
      Bl[(((kt * 4) + (kk >> 3)) * 128 + a) * 8 + (kk & 7)] = f2bf_rne(v);
    }
  }
}

// ---------------- main: depth-2 counted-vmcnt pipeline, A+B staged via global_load_lds
__global__ __launch_bounds__(256, 2) void lsa_main(
    const float* __restrict__ keys, const float* __restrict__ prev,
    const int* __restrict__ mask, const unsigned short* __restrict__ Bl,
    const float* __restrict__ pq, const float* __restrict__ Vv,
    float* __restrict__ wout, float* __restrict__ dpart, float* __restrict__ cpart) {
  __shared__ float Abuf[3][BM * BK];            // 3 x 16 KB fp32, chunk-swizzled
  __shared__ unsigned short Bbuf[3][ATT * BK];  // 3 x 8 KB bf16, chunk-major
  __shared__ float s_red[2][BM];
  __shared__ float e_vals[BM];

  const int tid = threadIdx.x;
  const int b = blockIdx.y;
  const int trow0 = blockIdx.x * BM;
  const int bid = b * NXB + blockIdx.x;

  const int lane = tid & 63;
  const int w = tid >> 6;
  const int wr = w >> 1, wc = w & 1;          // 2x2 waves, wave tile 64x64
  const int rsel = lane & 15, grp = lane >> 4;

  // A staging: lane covers row (w*32 + i*8 + lr), phys 16B chunk cp holds logical cp^lr
  const int lr = lane >> 3, cp = lane & 7;
  const int gc = cp ^ lr;
  const float* gA = keys + ((size_t)b * T_LEN + trow0 + w * 32 + lr) * ENC + gc * 4;

  // A fragment read: row r = wr*64 + m*16 + rsel; logical chunks 2g,2g+1; (r&7)==(rsel&7)
  const int rx = rsel & 7;
  const int ca0 = (2 * grp) ^ rx, ca1 = (2 * grp + 1) ^ rx;
  const int arow_base = (wr * 64 + rsel) * BK;

  // B fragment read (chunk-major): shorts offset (grp*128 + col)*8
  const int bcol_base = wc * 64 + rsel;

  f32x4 acc[4][4];
  #pragma unroll
  for (int m = 0; m < 4; ++m)
    #pragma unroll
    for (int n = 0; n < 4; ++n) acc[m][n] = (f32x4)0.f;

  // stage tile t into buffer buf: 4 A-loads + 2 B-loads per thread (6 vmem insts/wave)
  // NOTE: global source must be PER-LANE (gA embeds lane; B adds lane*8 shorts = lane*16B);
  // LDS dest is wave-uniform base (+ lane*16B applied by HW).
  auto STAGE = [&](int t, int buf) {
    const float* gt = gA + t * BK;
    float* dstA = &Abuf[buf][0];
    #pragma unroll
    for (int i = 0; i < 4; ++i)
      async_copy16(gt + (size_t)i * 8 * ENC, &dstA[(w * 4 + i) * 256]);
    const unsigned short* gBt = Bl + (size_t)t * (ATT * BK) + w * 1024 + lane * 8;
    unsigned short* dstB = &Bbuf[buf][0];
    #pragma unroll
    for (int j = 0; j < 2; ++j)
      async_copy16(gBt + j * 512, &dstB[w * 1024 + j * 512]);
  };

  auto COMPUTE = [&](int buf) {
    const unsigned short* Bb = &Bbuf[buf][0];
    bf16x8 bfr[4];
    #pragma unroll
    for (int n = 0; n < 4; ++n)
      bfr[n] = *reinterpret_cast<const bf16x8*>(&Bb[(grp * 128 + bcol_base + n * 16) * 8]);
    const float* Ab = &Abuf[buf][0];
    #pragma unroll
    for (int m = 0; m < 4; ++m) {
      f32x4 x0 = *reinterpret_cast<const f32x4*>(&Ab[arow_base + m * 16 * BK + ca0 * 4]);
      f32x4 x1 = *reinterpret_cast<const f32x4*>(&Ab[arow_base + m * 16 * BK + ca1 * 4]);
      bf16x8 af;
      #pragma unroll
      for (int j = 0; j < 4; ++j) { af[j] = f2bf_fast(x0[j]); af[4 + j] = f2bf_fast(x1[j]); }
      #pragma unroll
      for (int n = 0; n < 4; ++n)
        acc[m][n] = __builtin_amdgcn_mfma_f32_16x16x32_bf16(af, bfr[n], acc[m][n], 0, 0, 0);
    }
  };

  // ---- prologue: stage tiles 0,1; wait tile0 (leave tile1 in flight) ----
  STAGE(0, 0);
  STAGE(1, 1);
  asm volatile("s_waitcnt vmcnt(6)" ::: "memory");
  __builtin_amdgcn_s_barrier();
  __builtin_amdgcn_sched_barrier(0);

  // ---- main loop t = 0..13: issue stage(t+2), compute(t), wait stage(t+1) ----
  #pragma unroll
  for (int t = 0; t < 14; ++t) {
    STAGE(t + 2, (t + 2) % 3);
    COMPUTE(t % 3);
    asm volatile("s_waitcnt vmcnt(6)" ::: "memory");
    __builtin_amdgcn_s_barrier();
    __builtin_amdgcn_sched_barrier(0);
  }

  // ---- t = 14: stage conv tile (t=16 -> buf 1): B via gload_lds, A via ds_write ----
  {
    const unsigned short* gBt = Bl + (size_t)16 * (ATT * BK) + w * 1024 + lane * 8;
    unsigned short* dstB = &Bbuf[1][0];
    #pragma unroll
    for (int j = 0; j < 2; ++j)
      async_copy16(gBt + j * 512, &dstB[w * 1024 + j * 512]);
    // conv A: A16[r][kk] = prev[trow0 + r + kk - 15], kk<31, swizzled like regular A
    const int r_ = tid >> 1, kh_ = tid & 1;
    const int rx2_ = r_ & 7;
    float* dstA = &Abuf[1][r_ * BK];
    #pragma unroll
    for (int jc = 0; jc < 4; ++jc) {
      int c = kh_ * 4 + jc;
      f32x4 v;
      #pragma unroll
      for (int q = 0; q < 4; ++q) {
        int kk = c * 4 + q;
        int pos = trow0 + r_ + kk - 15;
        v[q] = (kk < 31 && pos >= 0 && pos < T_LEN) ? prev[b * T_LEN + pos] : 0.f;
      }
      *reinterpret_cast<f32x4*>(&dstA[(c ^ rx2_) * 4]) = v;
    }
    COMPUTE(14 % 3);
    __syncthreads();   // full vmcnt+lgkm drain: tiles 15,16 all resident after this
  }

  // ---- t = 15, 16: everything resident, no more barriers needed ----
  COMPUTE(15 % 3);
  COMPUTE(16 % 3);

  // ---- epilogue: scores = sum_a V[a]*tanh(acc + pq) ----
  float psum[4][4];
  #pragma unroll
  for (int m = 0; m < 4; ++m)
    #pragma unroll
    for (int i = 0; i < 4; ++i) psum[m][i] = 0.f;
  #pragma unroll
  for (int n = 0; n < 4; ++n) {
    int c = wc * 64 + n * 16 + rsel;
    float pqv = pq[b * ATT + c];
    float vv = Vv[c];
    #pragma unroll
    for (int m = 0; m < 4; ++m)
      #pragma unroll
      for (int i = 0; i < 4; ++i)
        psum[m][i] += vv * fast_tanh(acc[m][n][i] + pqv);
  }
  #pragma unroll
  for (int m = 0; m < 4; ++m)
    #pragma unroll
    for (int i = 0; i < 4; ++i) {
      float v = psum[m][i];
      v += __shfl_xor(v, 1, 64);
      v += __shfl_xor(v, 2, 64);
      v += __shfl_xor(v, 4, 64);
      v += __shfl_xor(v, 8, 64);
      psum[m][i] = v;
    }
  if (rsel == 0) {
    #pragma unroll
    for (int m = 0; m < 4; ++m)
      #pragma unroll
      for (int i = 0; i < 4; ++i)
        s_red[wc][wr * 64 + m * 16 + grp * 4 + i] = psum[m][i];
  }
  __syncthreads();

  if (tid < BM) {
    int trow = trow0 + tid;
    float s = s_red[0][tid] + s_red[1][tid];
    float e = (mask[b * T_LEN + trow] == 0) ? 0.f : __expf(s);
    wout[b * T_LEN + trow] = e;       // unnormalized; finalize scales
    e_vals[tid] = e;
  }
  __syncthreads();

  if (tid < 64) {
    float v = e_vals[tid] + e_vals[tid + 64];
    #pragma unroll
    for (int off = 32; off; off >>= 1) v += __shfl_xor(v, off, 64);
    if (tid == 0) dpart[bid] = v;
  }

  // ---- partial context: branch-free, float2, L2/L3-hot re-read of own tile ----
  {
    const float* kcol = keys + ((size_t)b * T_LEN + trow0) * ENC + 2 * tid;
    f32x2 cacc; cacc.x = 0.f; cacc.y = 0.f;
    #pragma unroll 8
    for (int r = 0; r < BM; ++r) {
      float e = e_vals[r];
      f32x2 kv = *reinterpret_cast<const f32x2*>(kcol + (size_t)r * ENC);
      cacc.x += e * kv.x;
      cacc.y += e * kv.y;
    }
    *reinterpret_cast<f32x2*>(cpart + (size_t)bid * ENC + 2 * tid) = cacc;
  }
}

// ---------------- finalize: normalize weights + reduce context partials
__global__ __launch_bounds__(256) void lsa_finalize(
    const float* __restrict__ dpart, const float* __restrict__ cpart,
    float* __restrict__ out) {
  int b = blockIdx.x, tid = threadIdx.x;
  float d = 0.f;
  #pragma unroll
  for (int i = 0; i < NXB; ++i) d += dpart[b * NXB + i];
  float inv = 1.f / d;
  for (int e = tid; e < ENC; e += 256) {
    float c = 0.f;
    #pragma unroll
    for (int i = 0; i < NXB; ++i) c += cpart[((size_t)(b * NXB + i)) * ENC + e];
    out[b * ENC + e] = c * inv;
  }
  float* wrow = out + NB * ENC + (size_t)b * T_LEN;
  for (int t = tid; t < T_LEN; t += 256) wrow[t] *= inv;
}

extern "C" void kernel_launch(void* const* d_in, const int* in_sizes, int n_in,
                              void* d_out, int out_size, void* d_ws, size_t ws_size,
                              hipStream_t stream) {
  const float* query  = (const float*)d_in[0];
  const float* keys   = (const float*)d_in[1];
  const float* prev   = (const float*)d_in[2];
  const int*   mask   = (const int*)d_in[3];
  const float* W1     = (const float*)d_in[4];
  const float* W2     = (const float*)d_in[5];
  const float* V      = (const float*)d_in[6];
  const float* convw  = (const float*)d_in[7];
  const float* ldense = (const float*)d_in[8];
  float* out = (float*)d_out;

  char* ws = (char*)d_ws;
  unsigned short* Bl = (unsigned short*)ws;                       // 139264 B
  float* pq    = (float*)(ws + 139264);                           // 32768 B
  float* dpart = (float*)(ws + 139264 + 32768);                   // 4096 B
  float* cpart = (float*)(ws + 139264 + 32768 + 4096);            // 2 MB

  prep<<<dim3(192), dim3(128), 0, stream>>>(query, W2, W1, convw, ldense, pq, Bl);
  dim3 grid(NXB, NB);
  lsa_main<<<grid, dim3(256), 0, stream>>>(keys, prev, mask, Bl, pq, V,
                                           out + NB * ENC, dpart, cpart);
  lsa_finalize<<<dim3(NB), dim3(256), 0, stream>>>(dpart, cpart, out);
}